// Round 16
// baseline (192.819 us; speedup 1.0000x reference)
//
#include <hip/hip_runtime.h>

typedef __attribute__((ext_vector_type(8))) short vbf8;   // 8 bf16 = 4 VGPR
typedef __attribute__((ext_vector_type(4))) float vf4;    // MFMA 16x16 accumulator

#define GLOAD16(g, l) __builtin_amdgcn_global_load_lds( \
    (const __attribute__((address_space(1))) void*)(g),  \
    (__attribute__((address_space(3))) void*)(l), 16, 0, 0)

__device__ __forceinline__ unsigned short f2bf(float f) {
  union { float f; unsigned u; } v; v.f = f;
  return (unsigned short)((v.u + 0x7fffu + ((v.u >> 16) & 1u)) >> 16);  // RNE
}

__device__ __forceinline__ unsigned short cvt_bf16(float f) {
  __bf16 h = (__bf16)f;            // hardware RNE convert on gfx950
  union { __bf16 h; unsigned short u; } v; v.h = h;
  return v.u;
}

__device__ __forceinline__ vf4 mfma16(vbf8 a, vbf8 b, vf4 c) {
  return __builtin_amdgcn_mfma_f32_16x16x32_bf16(a, b, c, 0, 0, 0);
}

// XOR-swizzle for a [64][64] u16 tile (T2 / G4 recipe: byte ^= (row&7)<<4).
__device__ __forceinline__ int swz(int row, int col) {
  return row * 64 + (col ^ ((row & 7) << 3));
}

// ---------------- fp32 -> bf16 convert: all three tensors in ONE launch ----------------
__global__ __launch_bounds__(256)
void k_cvt_all(const float* __restrict__ x, unsigned short* __restrict__ xo,
               const float* __restrict__ w1, unsigned short* __restrict__ w1o,
               const float* __restrict__ w2, unsigned short* __restrict__ w2o) {
  // float4 counts: x 2097152, w_qkv 786432, w_out 262144 (total 3145728)
  for (int i = blockIdx.x * blockDim.x + threadIdx.x; i < 3145728; i += gridDim.x * blockDim.x) {
    const float* in; unsigned short* out; int j;
    if (i < 2097152)      { in = x;  out = xo;  j = i; }
    else if (i < 2883584) { in = w1; out = w1o; j = i - 2097152; }
    else                  { in = w2; out = w2o; j = i - 2883584; }
    float4 v = ((const float4*)in)[j];
    ushort4 o;
    o.x = f2bf(v.x); o.y = f2bf(v.y); o.z = f2bf(v.z); o.w = f2bf(v.w);
    ((ushort4*)out)[j] = o;
  }
}

// ---------------- GEMM1: 4-phase 256x256 template (T2+T3+T4+T5, 1 K-tile/iter) ----------------
// qkv = xbf [8192,1024] @ wqkv^T [3072,1024]. BK=64, 512 thr / 8 waves (2Mx4N),
// per-wave 128x64 (acc[8][4]). LDS 128KB: {A,B} x dbuf x 2 halves x [128][64].
// Iter t consumes K-tile t from buf (t&1); 4 phases (kk,qm): ds-read af[4]
// (+bf[4] at qm=0, reused at qm=1) -> barrier -> lgkmcnt(0)+sched_barrier ->
// 16 MFMA (setprio) -> [vmcnt(0) at phase 3 for t<15] -> barrier.
// Stages for tile t+1 (8 gloads) issue in phases 0-1 -> ~2-phase drain distance.
// LDS (row&7) col-group XOR swizzle both sides (attn-proven pattern).
// Epilogue: q pre-scaled, k row-major, V -> vtbuf [BH,D,N] (transpose fused).
__global__ __launch_bounds__(512, 2)
void k_gemm_qkv(const unsigned short* __restrict__ A,
                const unsigned short* __restrict__ B,
                unsigned short* __restrict__ qb,
                unsigned short* __restrict__ kb,
                unsigned short* __restrict__ vtb) {
  __shared__ __attribute__((aligned(16))) unsigned short lds[65536];  // 128KB
  const int tid = threadIdx.x;
  const int lane = tid & 63;
  const int w = tid >> 6;                  // 0..7
  const int wm = w >> 2, wn = w & 3;       // 2M x 4N
  const int l15 = lane & 15, kg = lane >> 4;
  // XCD-aware bijective swizzle (384 blocks, 48 per XCD)
  const int flat = blockIdx.x;
  const int sw = (flat & 7) * 48 + (flat >> 3);
  const int m0 = (sw / 12) * 256;
  const int n0 = (sw % 12) * 256;

  // staging: lane -> row (lane>>3), col-group pre-swizzled by row&7 (involution)
  const int srow = lane >> 3;                  // 0..7
  const int scg = (lane & 7) ^ srow;
  const unsigned short* gA = A + (size_t)(m0 + w * 16 + srow) * 1024 + scg * 8;
  const unsigned short* gB = B + (size_t)(n0 + w * 16 + srow) * 1024 + scg * 8;
  const unsigned ldsw = (unsigned)(w * 16 * 64);   // wave dest offset within a half

  // stage half-tile: tensor T(0=A,1=B), K-tile kt, half h, buf b (2 gload_lds, 16 rows)
#define STG(T, kt, h, b) do { \
    const unsigned short* g_ = (T) ? gB : gA; \
    unsigned short* l_ = &lds[(T) * 32768 + ((b) * 2 + (h)) * 8192 + ldsw]; \
    GLOAD16(g_ + (size_t)((h) * 128) * 1024 + (kt) * 64,     l_); \
    GLOAD16(g_ + (size_t)((h) * 128 + 8) * 1024 + (kt) * 64, l_ + 8 * 64); \
  } while (0)

  // prologue: stage K-tile 0 into buf 0; full drain
  STG(0, 0, 0, 0); STG(1, 0, 0, 0); STG(0, 0, 1, 0); STG(1, 0, 1, 0);
  asm volatile("s_waitcnt vmcnt(0)" ::: "memory");
  __builtin_amdgcn_s_barrier();
  __builtin_amdgcn_sched_barrier(0);

  vf4 acc[8][4] = {};
  const int rsw = l15 & 7;

  for (int t = 0; t < 16; ++t) {
    const int b = t & 1;
    vbf8 bf[4];
#pragma unroll
    for (int kk = 0; kk < 2; ++kk) {
#pragma unroll
      for (int qm = 0; qm < 2; ++qm) {
        const int ph = kk * 2 + qm;          // 0..3
        // ds-reads from buf b (colgroup (kk*4+kg) ^ (l15&7), same as attn's swz)
        vbf8 af[4];
        const unsigned abase = (unsigned)((b * 2 + wm) * 8192);
#pragma unroll
        for (int mi = 0; mi < 4; ++mi)
          af[mi] = *(const vbf8*)&lds[abase + (qm * 64 + mi * 16 + l15) * 64 + ((kk * 4 + kg) ^ rsw) * 8];
        if (qm == 0) {
          const unsigned bbase = (unsigned)(32768 + (b * 2 + (wn >> 1)) * 8192);
#pragma unroll
          for (int nif = 0; nif < 4; ++nif)
            bf[nif] = *(const vbf8*)&lds[bbase + ((wn & 1) * 64 + nif * 16 + l15) * 64 + ((kk * 4 + kg) ^ rsw) * 8];
        }
        // stage tile t+1 into buf b^1: phases 0-1 issue all 4 half-tiles
        if (t < 15) {
          if (ph == 0) { STG(0, t + 1, 0, b ^ 1); STG(1, t + 1, 0, b ^ 1); }
          if (ph == 1) { STG(0, t + 1, 1, b ^ 1); STG(1, t + 1, 1, b ^ 1); }
        }

        __builtin_amdgcn_s_barrier();
        asm volatile("s_waitcnt lgkmcnt(0)" ::: "memory");
        __builtin_amdgcn_sched_barrier(0);   // rule #18: pin MFMA below the wait
        __builtin_amdgcn_s_setprio(1);
#pragma unroll
        for (int mi = 0; mi < 4; ++mi)
#pragma unroll
          for (int nif = 0; nif < 4; ++nif)
            acc[qm * 4 + mi][nif] = mfma16(af[mi], bf[nif], acc[qm * 4 + mi][nif]);
        __builtin_amdgcn_s_setprio(0);
        if (ph == 3 && t < 15)
          asm volatile("s_waitcnt vmcnt(0)" ::: "memory");  // tile t+1 landed
        __builtin_amdgcn_s_barrier();
      }
    }
  }
#undef STG

  // epilogue: c in [0,3072): which uniform per block (n0 multiple of 256)
#pragma unroll
  for (int nif = 0; nif < 4; ++nif) {
    const int c = n0 + wn * 64 + nif * 16 + l15;
    const int which = c >> 10;
    const int hd = c & 1023;
    const int h = hd >> 6, d = hd & 63;
#pragma unroll
    for (int mi = 0; mi < 8; ++mi) {
      const int m = m0 + wm * 128 + mi * 16 + kg * 4;
      const int bb = m >> 11, nn = m & 2047;
      if (which == 2) {
        // V^T [BH][D=64][N=2048]: r=0..3 -> consecutive nn -> one 8B store
        ushort4 pk;
        pk.x = f2bf(acc[mi][nif][0]);
        pk.y = f2bf(acc[mi][nif][1]);
        pk.z = f2bf(acc[mi][nif][2]);
        pk.w = f2bf(acc[mi][nif][3]);
        *(ushort4*)&vtb[((size_t)(bb * 16 + h) * 64 + d) * 2048 + nn] = pk;
      } else {
        unsigned short* dst = (which == 0) ? qb : kb;
        const float sc = (which == 0) ? 0.18033688011112042f : 1.0f;  // 0.125*log2(e) in q
#pragma unroll
        for (int r = 0; r < 4; ++r)
          dst[((size_t)(bb * 16 + h) * 2048 + nn + r) * 64 + d] = f2bf(acc[mi][nif][r] * sc);
      }
    }
  }
}

// ---------------- flash attention (R14-proven): per (bh, qtile of 256 rows), 8 waves ----------------
__global__ __launch_bounds__(512, 4)
void k_attn(const unsigned short* __restrict__ qb,
            const unsigned short* __restrict__ kb,
            const unsigned short* __restrict__ vt,
            unsigned short* __restrict__ ob) {
  __shared__ unsigned short Ks[2][64 * 64];
  __shared__ unsigned short Vs[64 * 64];      // V^T tile: [d][kv], single buffer
  __shared__ unsigned short Ps[8][32][64];    // per-wave P [q][kv], XOR-swizzled
  const int tid = threadIdx.x, lane = tid & 63, w = tid >> 6;   // w = 0..7
  const int l15 = lane & 15, kg = lane >> 4;
  // XCD-aware bijective swizzle: 512 blocks, each XCD owns 8 full bh
  const int flat = blockIdx.x;
  const int sw = (flat & 7) * 64 + (flat >> 3);
  const int qt = sw & 7, bh = sw >> 3;

  const unsigned short* Q = qb + ((size_t)bh * 2048 + qt * 256 + w * 32) * 64;
  vbf8 qf[2][2];
#pragma unroll
  for (int qj = 0; qj < 2; ++qj)
#pragma unroll
    for (int kk = 0; kk < 2; ++kk)
      qf[qj][kk] = *(const vbf8*)(Q + (qj * 16 + l15) * 64 + kk * 32 + kg * 8);

  vbf8 onesv;
#pragma unroll
  for (int i = 0; i < 8; ++i) onesv[i] = (short)0x3F80;  // bf16 1.0

  vf4 oacc[2][4] = {};   // [qj][d-block]: O[q=kg*4+r][d=ni*16+l15]
  vf4 lacc[2] = {};      // row-sum of P per subblock (pure accumulation, m=0)

  const int srow = lane >> 3;
  const int scol = (((lane & 7) ^ srow) * 8);
  const int pswz = (l15 & 7) << 3;
  // each wave stages rows w*8 .. w*8+7 (one gload_lds = 64 lanes x 16B = 8 rows)
  const unsigned short* gKbase = kb + ((size_t)bh * 2048 + w * 8 + srow) * 64 + scol;
  const unsigned short* gVbase = vt + ((size_t)bh * 64 + w * 8 + srow) * 2048 + scol;

#define STAGE_K(t, b) do { \
    GLOAD16(gKbase + (size_t)(t) * 4096, &Ks[b][(w * 8) * 64]); \
  } while (0)
#define STAGE_V(t) do { \
    GLOAD16(gVbase + (size_t)(t) * 64, &Vs[(w * 8) * 64]); \
  } while (0)

  STAGE_K(0, 0);
  asm volatile("s_waitcnt vmcnt(0)" ::: "memory");
  __builtin_amdgcn_s_barrier();
  __builtin_amdgcn_sched_barrier(0);

  for (int kt = 0; kt < 32; ++kt) {
    const int cur = kt & 1;
    STAGE_V(kt);                                   // 1 load (oldest)
    if (kt + 1 < 32) STAGE_K(kt + 1, cur ^ 1);     // 1 load, in flight to iter end

    // hoist K fragments once per tile
    vbf8 kfr[2][4];
#pragma unroll
    for (int kk = 0; kk < 2; ++kk)
#pragma unroll
      for (int ni = 0; ni < 4; ++ni)
        kfr[kk][ni] = *(const vbf8*)&Ks[cur][swz(ni * 16 + l15, kk * 32 + kg * 8)];

    // S^T = K @ Q^T (lane holds S[kv][q=l15]); Q pre-scaled by 0.125*log2e
    vf4 s[2][4] = {};
    __builtin_amdgcn_s_setprio(1);
#pragma unroll
    for (int kk = 0; kk < 2; ++kk)
#pragma unroll
      for (int ni = 0; ni < 4; ++ni) {
        s[0][ni] = mfma16(kfr[kk][ni], qf[0][kk], s[0][ni]);
        s[1][ni] = mfma16(kfr[kk][ni], qf[1][kk], s[1][ni]);
      }
    __builtin_amdgcn_s_setprio(0);

    // P = exp2(S) -> bf16 (m=0: no max, no rescale, exact telescoping)
#pragma unroll
    for (int qj = 0; qj < 2; ++qj)
#pragma unroll
      for (int ni = 0; ni < 4; ++ni) {
        ushort4 pk;
        pk.x = cvt_bf16(__builtin_amdgcn_exp2f(s[qj][ni][0]));
        pk.y = cvt_bf16(__builtin_amdgcn_exp2f(s[qj][ni][1]));
        pk.z = cvt_bf16(__builtin_amdgcn_exp2f(s[qj][ni][2]));
        pk.w = cvt_bf16(__builtin_amdgcn_exp2f(s[qj][ni][3]));
        *(ushort4*)&Ps[w][qj * 16 + l15][(ni * 16 + kg * 4) ^ pswz] = pk;
      }

    // wait: own P-writes (lgkm) + V load (oldest vm); K(t+1) stays in flight
    if (kt + 1 < 32) asm volatile("s_waitcnt vmcnt(1) lgkmcnt(0)" ::: "memory");
    else             asm volatile("s_waitcnt vmcnt(0) lgkmcnt(0)" ::: "memory");
    __builtin_amdgcn_s_barrier();      // all waves' V rows landed
    __builtin_amdgcn_sched_barrier(0); // keep PV ds_reads below the barrier

    // O += P @ V ; l += P @ ones  (V fragments shared across both subblocks)
    __builtin_amdgcn_s_setprio(1);
#pragma unroll
    for (int kk = 0; kk < 2; ++kk) {
      const vbf8 pf0 = *(const vbf8*)&Ps[w][l15][(kk * 32 + kg * 8) ^ pswz];
      const vbf8 pf1 = *(const vbf8*)&Ps[w][16 + l15][(kk * 32 + kg * 8) ^ pswz];
      lacc[0] = mfma16(pf0, onesv, lacc[0]);
      lacc[1] = mfma16(pf1, onesv, lacc[1]);
#pragma unroll
      for (int ni = 0; ni < 4; ++ni) {
        const vbf8 vf = *(const vbf8*)&Vs[swz(ni * 16 + l15, kk * 32 + kg * 8)];
        oacc[0][ni] = mfma16(pf0, vf, oacc[0][ni]);
        oacc[1][ni] = mfma16(pf1, vf, oacc[1][ni]);
      }
    }
    __builtin_amdgcn_s_setprio(0);

    __syncthreads();   // drains K(t+1) (vmcnt 0), frees Vs for next stage
  }
#undef STAGE_K
#undef STAGE_V

  const int b = bh >> 4, h = bh & 15;
#pragma unroll
  for (int qj = 0; qj < 2; ++qj)
#pragma unroll
    for (int r = 0; r < 4; ++r) {
      const float inv = 1.0f / lacc[qj][r];
      const int q = qt * 256 + w * 32 + qj * 16 + kg * 4 + r;
#pragma unroll
      for (int ni = 0; ni < 4; ++ni)
        ob[((size_t)b * 2048 + q) * 1024 + h * 64 + ni * 16 + l15] = cvt_bf16(oacc[qj][ni][r] * inv);
    }
}

// ---------------- GEMM2 (m97 structure): out = attnO @ wout^T + bias (f32 out) ----------------
__global__ __launch_bounds__(256, 2)
void k_gemm_out(const unsigned short* __restrict__ A,
                const unsigned short* __restrict__ B,
                const float* __restrict__ bias,
                float* __restrict__ out) {
  __shared__ unsigned short As[128 * 64];
  __shared__ unsigned short Bs[128 * 64];
  const int tid = threadIdx.x;
  const int lane = tid & 63;
  const int wid = tid >> 6;
  const int wm = wid >> 1, wn = wid & 1;
  // XCD-aware bijective swizzle (nwg = 8*64 = 512, %8==0)
  const int flat = blockIdx.y * 8 + blockIdx.x;
  const int sw = (flat & 7) * 64 + (flat >> 3);
  const int m0 = (sw / 8) * 128;
  const int n0 = (sw % 8) * 128;
  const int l15 = lane & 15, kg = lane >> 4;
  const int srow = wid * 32 + (lane >> 3);
  const int scol = (lane & 7) * 8;

  vf4 acc[4][4] = {};

  for (int kt = 0; kt < 16; ++kt) {
    __syncthreads();
    const unsigned short* gA = A + (size_t)(m0 + srow) * 1024 + kt * 64 + scol;
    const unsigned short* gB = B + (size_t)(n0 + srow) * 1024 + kt * 64 + scol;
    const unsigned ab = (unsigned)(wid * 32 * 64);
#pragma unroll
    for (int i = 0; i < 4; ++i) {
      GLOAD16(gA + (size_t)i * 8 * 1024, &As[ab + i * 8 * 64]);
      GLOAD16(gB + (size_t)i * 8 * 1024, &Bs[ab + i * 8 * 64]);
    }
    __syncthreads();
#pragma unroll
    for (int kk = 0; kk < 2; ++kk) {
      vbf8 af[4], bfr[4];
#pragma unroll
      for (int mi = 0; mi < 4; ++mi)
        af[mi] = *(const vbf8*)&As[(wm * 64 + mi * 16 + l15) * 64 + kk * 32 + kg * 8];
#pragma unroll
      for (int ni = 0; ni < 4; ++ni)
        bfr[ni] = *(const vbf8*)&Bs[(wn * 64 + ni * 16 + l15) * 64 + kk * 32 + kg * 8];
#pragma unroll
      for (int mi = 0; mi < 4; ++mi)
#pragma unroll
        for (int ni = 0; ni < 4; ++ni)
          acc[mi][ni] = mfma16(af[mi], bfr[ni], acc[mi][ni]);
    }
  }

#pragma unroll
  for (int ni = 0; ni < 4; ++ni) {
    const int c = n0 + wn * 64 + ni * 16 + l15;
    const float bv = bias[c];
#pragma unroll
    for (int mi = 0; mi < 4; ++mi) {
#pragma unroll
      for (int r = 0; r < 4; ++r) {
        const int m = m0 + wm * 64 + mi * 16 + kg * 4 + r;
        out[(size_t)m * 1024 + c] = acc[mi][ni][r] + bv;
      }
    }
  }
}

extern "C" void kernel_launch(void* const* d_in, const int* in_sizes, int n_in,
                              void* d_out, int out_size, void* d_ws, size_t ws_size,
                              hipStream_t stream) {
  const float* x     = (const float*)d_in[0];
  const float* w_qkv = (const float*)d_in[1];
  const float* w_out = (const float*)d_in[2];
  const float* b_out = (const float*)d_in[3];
  float* out = (float*)d_out;

  char* ws = (char*)d_ws;
  unsigned short* xbf   = (unsigned short*)(ws);                       // 16 MB (aliased as attnO later)
  unsigned short* wqkvb = (unsigned short*)(ws + 16777216);            // 6 MB
  unsigned short* woutb = (unsigned short*)(ws + 23068672);            // 2 MB
  unsigned short* qbuf  = (unsigned short*)(ws + 25165824);            // 16 MB
  unsigned short* kbuf  = (unsigned short*)(ws + 41943040);            // 16 MB
  unsigned short* vtbuf = (unsigned short*)(ws + 75497472);            // 16 MB (V^T, written by gemm_qkv)
  unsigned short* aob   = xbf;  // attn output aliases xbf (xbf dead after GEMM1)

  k_cvt_all<<<2048, 256, 0, stream>>>(x, xbf, w_qkv, wqkvb, w_out, woutb);

  k_gemm_qkv<<<dim3(384), 512, 0, stream>>>(xbf, wqkvb, qbuf, kbuf, vtbuf);
  k_attn<<<dim3(512), 512, 0, stream>>>(qbuf, kbuf, vtbuf, aob);
  k_gemm_out<<<dim3(8, 64), 256, 0, stream>>>(aob, woutb, b_out, out);
}

// Round 17
// 185.679 us; speedup vs baseline: 1.0385x; 1.0385x over previous
//
#include <hip/hip_runtime.h>

typedef __attribute__((ext_vector_type(8))) short vbf8;   // 8 bf16 = 4 VGPR
typedef __attribute__((ext_vector_type(4))) float vf4;    // MFMA 16x16 accumulator

#define GLOAD16(g, l) __builtin_amdgcn_global_load_lds( \
    (const __attribute__((address_space(1))) void*)(g),  \
    (__attribute__((address_space(3))) void*)(l), 16, 0, 0)

__device__ __forceinline__ unsigned short f2bf(float f) {
  union { float f; unsigned u; } v; v.f = f;
  return (unsigned short)((v.u + 0x7fffu + ((v.u >> 16) & 1u)) >> 16);  // RNE
}

__device__ __forceinline__ unsigned short cvt_bf16(float f) {
  __bf16 h = (__bf16)f;            // hardware RNE convert on gfx950
  union { __bf16 h; unsigned short u; } v; v.h = h;
  return v.u;
}

__device__ __forceinline__ vf4 mfma16(vbf8 a, vbf8 b, vf4 c) {
  return __builtin_amdgcn_mfma_f32_16x16x32_bf16(a, b, c, 0, 0, 0);
}

// XOR-swizzle for a [64][64] u16 tile (T2 / G4 recipe: byte ^= (row&7)<<4).
__device__ __forceinline__ int swz(int row, int col) {
  return row * 64 + (col ^ ((row & 7) << 3));
}

// ---------------- fp32 -> bf16 convert: all three tensors in ONE launch ----------------
__global__ __launch_bounds__(256)
void k_cvt_all(const float* __restrict__ x, unsigned short* __restrict__ xo,
               const float* __restrict__ w1, unsigned short* __restrict__ w1o,
               const float* __restrict__ w2, unsigned short* __restrict__ w2o) {
  // float4 counts: x 2097152, w_qkv 786432, w_out 262144 (total 3145728)
  for (int i = blockIdx.x * blockDim.x + threadIdx.x; i < 3145728; i += gridDim.x * blockDim.x) {
    const float* in; unsigned short* out; int j;
    if (i < 2097152)      { in = x;  out = xo;  j = i; }
    else if (i < 2883584) { in = w1; out = w1o; j = i - 2097152; }
    else                  { in = w2; out = w2o; j = i - 2883584; }
    float4 v = ((const float4*)in)[j];
    ushort4 o;
    o.x = f2bf(v.x); o.y = f2bf(v.y); o.z = f2bf(v.z); o.w = f2bf(v.w);
    ((ushort4*)out)[j] = o;
  }
}

// ---------------- GEMM1 (m97 structure, R14-proven): qkv = xbf @ wqkv^T ----------------
// Epilogue: q (pre-scaled) / k -> [BH,N,D]; V -> vtbuf [BH,D,N] DIRECTLY
// (transpose fused; r=0..3 are consecutive nn -> packed ushort4 stores).
__global__ __launch_bounds__(256, 2)
void k_gemm_qkv(const unsigned short* __restrict__ A,
                const unsigned short* __restrict__ B,
                unsigned short* __restrict__ qb,
                unsigned short* __restrict__ kb,
                unsigned short* __restrict__ vtb) {
  __shared__ unsigned short As[128 * 64];
  __shared__ unsigned short Bs[128 * 64];
  const int tid = threadIdx.x;
  const int lane = tid & 63;
  const int wid = tid >> 6;
  const int wm = wid >> 1, wn = wid & 1;
  // XCD-aware bijective swizzle (nwg = 24*64 = 1536, %8==0)
  const int flat = blockIdx.y * 24 + blockIdx.x;
  const int sw = (flat & 7) * 192 + (flat >> 3);
  const int m0 = (sw / 24) * 128;
  const int n0 = (sw % 24) * 128;
  const int l15 = lane & 15, kg = lane >> 4;
  const int srow = wid * 32 + (lane >> 3);
  const int scol = (lane & 7) * 8;

  vf4 acc[4][4] = {};

  for (int kt = 0; kt < 16; ++kt) {
    __syncthreads();
    const unsigned short* gA = A + (size_t)(m0 + srow) * 1024 + kt * 64 + scol;
    const unsigned short* gB = B + (size_t)(n0 + srow) * 1024 + kt * 64 + scol;
    const unsigned ab = (unsigned)(wid * 32 * 64);
#pragma unroll
    for (int i = 0; i < 4; ++i) {
      GLOAD16(gA + (size_t)i * 8 * 1024, &As[ab + i * 8 * 64]);
      GLOAD16(gB + (size_t)i * 8 * 1024, &Bs[ab + i * 8 * 64]);
    }
    __syncthreads();
#pragma unroll
    for (int kk = 0; kk < 2; ++kk) {
      vbf8 af[4], bfr[4];
#pragma unroll
      for (int mi = 0; mi < 4; ++mi)
        af[mi] = *(const vbf8*)&As[(wm * 64 + mi * 16 + l15) * 64 + kk * 32 + kg * 8];
#pragma unroll
      for (int ni = 0; ni < 4; ++ni)
        bfr[ni] = *(const vbf8*)&Bs[(wn * 64 + ni * 16 + l15) * 64 + kk * 32 + kg * 8];
#pragma unroll
      for (int mi = 0; mi < 4; ++mi)
#pragma unroll
        for (int ni = 0; ni < 4; ++ni)
          acc[mi][ni] = mfma16(af[mi], bfr[ni], acc[mi][ni]);
    }
  }

  // epilogue: c in [0,3072): which=c>>10, h=(c>>6)&15, d=c&63
#pragma unroll
  for (int ni = 0; ni < 4; ++ni) {
    const int c = n0 + wn * 64 + ni * 16 + l15;
    const int which = c >> 10;
    const int hd = c & 1023;
    const int h = hd >> 6, d = hd & 63;
#pragma unroll
    for (int mi = 0; mi < 4; ++mi) {
      if (which == 2) {
        // V^T [BH][D=64][N=2048]: r=0..3 -> consecutive nn -> one 8B store
        const int m = m0 + wm * 64 + mi * 16 + kg * 4;
        const int b = m >> 11, nn = m & 2047;
        ushort4 pk;
        pk.x = f2bf(acc[mi][ni][0]);
        pk.y = f2bf(acc[mi][ni][1]);
        pk.z = f2bf(acc[mi][ni][2]);
        pk.w = f2bf(acc[mi][ni][3]);
        *(ushort4*)&vtb[((size_t)(b * 16 + h) * 64 + d) * 2048 + nn] = pk;
      } else {
        unsigned short* dst = (which == 0) ? qb : kb;
        const float sc = (which == 0) ? 0.18033688011112042f : 1.0f;  // 0.125*log2(e) in q
#pragma unroll
        for (int r = 0; r < 4; ++r) {
          const int m = m0 + wm * 64 + mi * 16 + kg * 4 + r;
          const int b = m >> 11, nn = m & 2047;
          dst[(((size_t)(b * 16 + h)) * 2048 + nn) * 64 + d] = f2bf(acc[mi][ni][r] * sc);
        }
      }
    }
  }
}

// ---------------- flash attention (R14-proven): per (bh, qtile of 256 rows), 8 waves ----------------
// 8 waves x 32 Q rows (2 subblocks each); KVBLK=64; m=0 softmax; K dbuf + V
// single-buffer LDS. 8-wave blocks halve per-CU K/V staging volume (each
// 64x64 tile staged once per 8 waves; one gload_lds per wave per tile).
__global__ __launch_bounds__(512, 4)
void k_attn(const unsigned short* __restrict__ qb,
            const unsigned short* __restrict__ kb,
            const unsigned short* __restrict__ vt,
            unsigned short* __restrict__ ob) {
  __shared__ unsigned short Ks[2][64 * 64];
  __shared__ unsigned short Vs[64 * 64];      // V^T tile: [d][kv], single buffer
  __shared__ unsigned short Ps[8][32][64];    // per-wave P [q][kv], XOR-swizzled
  const int tid = threadIdx.x, lane = tid & 63, w = tid >> 6;   // w = 0..7
  const int l15 = lane & 15, kg = lane >> 4;
  // XCD-aware bijective swizzle: 512 blocks, each XCD owns 8 full bh
  const int flat = blockIdx.x;
  const int sw = (flat & 7) * 64 + (flat >> 3);
  const int qt = sw & 7, bh = sw >> 3;

  const unsigned short* Q = qb + ((size_t)bh * 2048 + qt * 256 + w * 32) * 64;
  vbf8 qf[2][2];
#pragma unroll
  for (int qj = 0; qj < 2; ++qj)
#pragma unroll
    for (int kk = 0; kk < 2; ++kk)
      qf[qj][kk] = *(const vbf8*)(Q + (qj * 16 + l15) * 64 + kk * 32 + kg * 8);

  vbf8 onesv;
#pragma unroll
  for (int i = 0; i < 8; ++i) onesv[i] = (short)0x3F80;  // bf16 1.0

  vf4 oacc[2][4] = {};   // [qj][d-block]: O[q=kg*4+r][d=ni*16+l15]
  vf4 lacc[2] = {};      // row-sum of P per subblock (pure accumulation, m=0)

  const int srow = lane >> 3;
  const int scol = (((lane & 7) ^ srow) * 8);
  const int pswz = (l15 & 7) << 3;
  // each wave stages rows w*8 .. w*8+7 (one gload_lds = 64 lanes x 16B = 8 rows)
  const unsigned short* gKbase = kb + ((size_t)bh * 2048 + w * 8 + srow) * 64 + scol;
  const unsigned short* gVbase = vt + ((size_t)bh * 64 + w * 8 + srow) * 2048 + scol;

#define STAGE_K(t, b) do { \
    GLOAD16(gKbase + (size_t)(t) * 4096, &Ks[b][(w * 8) * 64]); \
  } while (0)
#define STAGE_V(t) do { \
    GLOAD16(gVbase + (size_t)(t) * 64, &Vs[(w * 8) * 64]); \
  } while (0)

  STAGE_K(0, 0);
  asm volatile("s_waitcnt vmcnt(0)" ::: "memory");
  __builtin_amdgcn_s_barrier();
  __builtin_amdgcn_sched_barrier(0);

  for (int kt = 0; kt < 32; ++kt) {
    const int cur = kt & 1;
    STAGE_V(kt);                                   // 1 load (oldest)
    if (kt + 1 < 32) STAGE_K(kt + 1, cur ^ 1);     // 1 load, in flight to iter end

    // hoist K fragments once per tile
    vbf8 kfr[2][4];
#pragma unroll
    for (int kk = 0; kk < 2; ++kk)
#pragma unroll
      for (int ni = 0; ni < 4; ++ni)
        kfr[kk][ni] = *(const vbf8*)&Ks[cur][swz(ni * 16 + l15, kk * 32 + kg * 8)];

    // S^T = K @ Q^T (lane holds S[kv][q=l15]); Q pre-scaled by 0.125*log2e
    vf4 s[2][4] = {};
    __builtin_amdgcn_s_setprio(1);
#pragma unroll
    for (int kk = 0; kk < 2; ++kk)
#pragma unroll
      for (int ni = 0; ni < 4; ++ni) {
        s[0][ni] = mfma16(kfr[kk][ni], qf[0][kk], s[0][ni]);
        s[1][ni] = mfma16(kfr[kk][ni], qf[1][kk], s[1][ni]);
      }
    __builtin_amdgcn_s_setprio(0);

    // P = exp2(S) -> bf16 (m=0: no max, no rescale, exact telescoping)
#pragma unroll
    for (int qj = 0; qj < 2; ++qj)
#pragma unroll
      for (int ni = 0; ni < 4; ++ni) {
        ushort4 pk;
        pk.x = cvt_bf16(__builtin_amdgcn_exp2f(s[qj][ni][0]));
        pk.y = cvt_bf16(__builtin_amdgcn_exp2f(s[qj][ni][1]));
        pk.z = cvt_bf16(__builtin_amdgcn_exp2f(s[qj][ni][2]));
        pk.w = cvt_bf16(__builtin_amdgcn_exp2f(s[qj][ni][3]));
        *(ushort4*)&Ps[w][qj * 16 + l15][(ni * 16 + kg * 4) ^ pswz] = pk;
      }

    // wait: own P-writes (lgkm) + V load (oldest vm); K(t+1) stays in flight
    if (kt + 1 < 32) asm volatile("s_waitcnt vmcnt(1) lgkmcnt(0)" ::: "memory");
    else             asm volatile("s_waitcnt vmcnt(0) lgkmcnt(0)" ::: "memory");
    __builtin_amdgcn_s_barrier();      // all waves' V rows landed
    __builtin_amdgcn_sched_barrier(0); // keep PV ds_reads below the barrier

    // O += P @ V ; l += P @ ones  (V fragments shared across both subblocks)
    __builtin_amdgcn_s_setprio(1);
#pragma unroll
    for (int kk = 0; kk < 2; ++kk) {
      const vbf8 pf0 = *(const vbf8*)&Ps[w][l15][(kk * 32 + kg * 8) ^ pswz];
      const vbf8 pf1 = *(const vbf8*)&Ps[w][16 + l15][(kk * 32 + kg * 8) ^ pswz];
      lacc[0] = mfma16(pf0, onesv, lacc[0]);
      lacc[1] = mfma16(pf1, onesv, lacc[1]);
#pragma unroll
      for (int ni = 0; ni < 4; ++ni) {
        const vbf8 vf = *(const vbf8*)&Vs[swz(ni * 16 + l15, kk * 32 + kg * 8)];
        oacc[0][ni] = mfma16(pf0, vf, oacc[0][ni]);
        oacc[1][ni] = mfma16(pf1, vf, oacc[1][ni]);
      }
    }
    __builtin_amdgcn_s_setprio(0);

    __syncthreads();   // drains K(t+1) (vmcnt 0), frees Vs for next stage
  }
#undef STAGE_K
#undef STAGE_V

  const int b = bh >> 4, h = bh & 15;
#pragma unroll
  for (int qj = 0; qj < 2; ++qj)
#pragma unroll
    for (int r = 0; r < 4; ++r) {
      const float inv = 1.0f / lacc[qj][r];
      const int q = qt * 256 + w * 32 + qj * 16 + kg * 4 + r;
#pragma unroll
      for (int ni = 0; ni < 4; ++ni)
        ob[((size_t)b * 2048 + q) * 1024 + h * 64 + ni * 16 + l15] = cvt_bf16(oacc[qj][ni][r] * inv);
    }
}

// ---------------- GEMM2 (m97 structure): out = attnO @ wout^T + bias (f32 out) ----------------
__global__ __launch_bounds__(256, 2)
void k_gemm_out(const unsigned short* __restrict__ A,
                const unsigned short* __restrict__ B,
                const float* __restrict__ bias,
                float* __restrict__ out) {
  __shared__ unsigned short As[128 * 64];
  __shared__ unsigned short Bs[128 * 64];
  const int tid = threadIdx.x;
  const int lane = tid & 63;
  const int wid = tid >> 6;
  const int wm = wid >> 1, wn = wid & 1;
  // XCD-aware bijective swizzle (nwg = 8*64 = 512, %8==0)
  const int flat = blockIdx.y * 8 + blockIdx.x;
  const int sw = (flat & 7) * 64 + (flat >> 3);
  const int m0 = (sw / 8) * 128;
  const int n0 = (sw % 8) * 128;
  const int l15 = lane & 15, kg = lane >> 4;
  const int srow = wid * 32 + (lane >> 3);
  const int scol = (lane & 7) * 8;

  vf4 acc[4][4] = {};

  for (int kt = 0; kt < 16; ++kt) {
    __syncthreads();
    const unsigned short* gA = A + (size_t)(m0 + srow) * 1024 + kt * 64 + scol;
    const unsigned short* gB = B + (size_t)(n0 + srow) * 1024 + kt * 64 + scol;
    const unsigned ab = (unsigned)(wid * 32 * 64);
#pragma unroll
    for (int i = 0; i < 4; ++i) {
      GLOAD16(gA + (size_t)i * 8 * 1024, &As[ab + i * 8 * 64]);
      GLOAD16(gB + (size_t)i * 8 * 1024, &Bs[ab + i * 8 * 64]);
    }
    __syncthreads();
#pragma unroll
    for (int kk = 0; kk < 2; ++kk) {
      vbf8 af[4], bfr[4];
#pragma unroll
      for (int mi = 0; mi < 4; ++mi)
        af[mi] = *(const vbf8*)&As[(wm * 64 + mi * 16 + l15) * 64 + kk * 32 + kg * 8];
#pragma unroll
      for (int ni = 0; ni < 4; ++ni)
        bfr[ni] = *(const vbf8*)&Bs[(wn * 64 + ni * 16 + l15) * 64 + kk * 32 + kg * 8];
#pragma unroll
      for (int mi = 0; mi < 4; ++mi)
#pragma unroll
        for (int ni = 0; ni < 4; ++ni)
          acc[mi][ni] = mfma16(af[mi], bfr[ni], acc[mi][ni]);
    }
  }

#pragma unroll
  for (int ni = 0; ni < 4; ++ni) {
    const int c = n0 + wn * 64 + ni * 16 + l15;
    const float bv = bias[c];
#pragma unroll
    for (int mi = 0; mi < 4; ++mi) {
#pragma unroll
      for (int r = 0; r < 4; ++r) {
        const int m = m0 + wm * 64 + mi * 16 + kg * 4 + r;
        out[(size_t)m * 1024 + c] = acc[mi][ni][r] + bv;
      }
    }
  }
}

extern "C" void kernel_launch(void* const* d_in, const int* in_sizes, int n_in,
                              void* d_out, int out_size, void* d_ws, size_t ws_size,
                              hipStream_t stream) {
  const float* x     = (const float*)d_in[0];
  const float* w_qkv = (const float*)d_in[1];
  const float* w_out = (const float*)d_in[2];
  const float* b_out = (const float*)d_in[3];
  float* out = (float*)d_out;

  char* ws = (char*)d_ws;
  unsigned short* xbf   = (unsigned short*)(ws);                       // 16 MB (aliased as attnO later)
  unsigned short* wqkvb = (unsigned short*)(ws + 16777216);            // 6 MB
  unsigned short* woutb = (unsigned short*)(ws + 23068672);            // 2 MB
  unsigned short* qbuf  = (unsigned short*)(ws + 25165824);            // 16 MB
  unsigned short* kbuf  = (unsigned short*)(ws + 41943040);            // 16 MB
  unsigned short* vtbuf = (unsigned short*)(ws + 75497472);            // 16 MB (V^T, written by gemm_qkv)
  unsigned short* aob   = xbf;  // attn output aliases xbf (xbf dead after GEMM1)

  k_cvt_all<<<2048, 256, 0, stream>>>(x, xbf, w_qkv, wqkvb, w_out, woutb);

  k_gemm_qkv<<<dim3(24, 64), 256, 0, stream>>>(xbf, wqkvb, qbuf, kbuf, vtbuf);
  k_attn<<<dim3(512), 512, 0, stream>>>(qbuf, kbuf, vtbuf, aob);
  k_gemm_out<<<dim3(8, 64), 256, 0, stream>>>(aob, woutb, b_out, out);
}

// Round 18
// 184.122 us; speedup vs baseline: 1.0472x; 1.0085x over previous
//
#include <hip/hip_runtime.h>

typedef __attribute__((ext_vector_type(8))) short vbf8;   // 8 bf16 = 4 VGPR
typedef __attribute__((ext_vector_type(4))) float vf4;    // MFMA 16x16 accumulator

#define GLOAD16(g, l) __builtin_amdgcn_global_load_lds( \
    (const __attribute__((address_space(1))) void*)(g),  \
    (__attribute__((address_space(3))) void*)(l), 16, 0, 0)

__device__ __forceinline__ unsigned short f2bf(float f) {
  union { float f; unsigned u; } v; v.f = f;
  return (unsigned short)((v.u + 0x7fffu + ((v.u >> 16) & 1u)) >> 16);  // RNE
}

__device__ __forceinline__ unsigned short cvt_bf16(float f) {
  __bf16 h = (__bf16)f;            // hardware RNE convert on gfx950
  union { __bf16 h; unsigned short u; } v; v.h = h;
  return v.u;
}

__device__ __forceinline__ vf4 mfma16(vbf8 a, vbf8 b, vf4 c) {
  return __builtin_amdgcn_mfma_f32_16x16x32_bf16(a, b, c, 0, 0, 0);
}

// XOR-swizzle for a [64][64] u16 tile (T2 / G4 recipe: byte ^= (row&7)<<4).
__device__ __forceinline__ int swz(int row, int col) {
  return row * 64 + (col ^ ((row & 7) << 3));
}

// ---------------- fp32 -> bf16 convert: all three tensors in ONE launch ----------------
__global__ __launch_bounds__(256)
void k_cvt_all(const float* __restrict__ x, unsigned short* __restrict__ xo,
               const float* __restrict__ w1, unsigned short* __restrict__ w1o,
               const float* __restrict__ w2, unsigned short* __restrict__ w2o) {
  // float4 counts: x 2097152, w_qkv 786432, w_out 262144 (total 3145728)
  for (int i = blockIdx.x * blockDim.x + threadIdx.x; i < 3145728; i += gridDim.x * blockDim.x) {
    const float* in; unsigned short* out; int j;
    if (i < 2097152)      { in = x;  out = xo;  j = i; }
    else if (i < 2883584) { in = w1; out = w1o; j = i - 2097152; }
    else                  { in = w2; out = w2o; j = i - 2883584; }
    float4 v = ((const float4*)in)[j];
    ushort4 o;
    o.x = f2bf(v.x); o.y = f2bf(v.y); o.z = f2bf(v.z); o.w = f2bf(v.w);
    ((ushort4*)out)[j] = o;
  }
}

// ---------------- GEMM1 (m97 structure): qkv = xbf @ wqkv^T ----------------
// XCD L2 blocking: 4x2 regions of 16m x 12n per XCD (A 4MB + B 3MB unique;
// n-fast order inside region -> instantaneous working set ~3.5MB, fits 4MB L2).
// Epilogue: q (pre-scaled) / k -> [BH,N,D]; V -> vtbuf [BH,D,N] (transpose fused).
__global__ __launch_bounds__(256, 2)
void k_gemm_qkv(const unsigned short* __restrict__ A,
                const unsigned short* __restrict__ B,
                unsigned short* __restrict__ qb,
                unsigned short* __restrict__ kb,
                unsigned short* __restrict__ vtb) {
  __shared__ unsigned short As[128 * 64];
  __shared__ unsigned short Bs[128 * 64];
  const int tid = threadIdx.x;
  const int lane = tid & 63;
  const int wid = tid >> 6;
  const int wm = wid >> 1, wn = wid & 1;
  // XCD-aware blocking: xcd = flat&7 -> region (mr,nr) = (xcd&3, xcd>>2);
  // within region (192 tiles): n-fast (12 wide), m slow (16 tall). Bijective.
  const int flat = blockIdx.y * 24 + blockIdx.x;
  const int xcd = flat & 7, idx = flat >> 3;
  const int m0 = ((xcd & 3) * 16 + idx / 12) * 128;
  const int n0 = ((xcd >> 2) * 12 + idx % 12) * 128;
  const int l15 = lane & 15, kg = lane >> 4;
  const int srow = wid * 32 + (lane >> 3);
  const int scol = (lane & 7) * 8;

  vf4 acc[4][4] = {};

  for (int kt = 0; kt < 16; ++kt) {
    __syncthreads();
    const unsigned short* gA = A + (size_t)(m0 + srow) * 1024 + kt * 64 + scol;
    const unsigned short* gB = B + (size_t)(n0 + srow) * 1024 + kt * 64 + scol;
    const unsigned ab = (unsigned)(wid * 32 * 64);
#pragma unroll
    for (int i = 0; i < 4; ++i) {
      GLOAD16(gA + (size_t)i * 8 * 1024, &As[ab + i * 8 * 64]);
      GLOAD16(gB + (size_t)i * 8 * 1024, &Bs[ab + i * 8 * 64]);
    }
    __syncthreads();
#pragma unroll
    for (int kk = 0; kk < 2; ++kk) {
      vbf8 af[4], bfr[4];
#pragma unroll
      for (int mi = 0; mi < 4; ++mi)
        af[mi] = *(const vbf8*)&As[(wm * 64 + mi * 16 + l15) * 64 + kk * 32 + kg * 8];
#pragma unroll
      for (int ni = 0; ni < 4; ++ni)
        bfr[ni] = *(const vbf8*)&Bs[(wn * 64 + ni * 16 + l15) * 64 + kk * 32 + kg * 8];
#pragma unroll
      for (int mi = 0; mi < 4; ++mi)
#pragma unroll
        for (int ni = 0; ni < 4; ++ni)
          acc[mi][ni] = mfma16(af[mi], bfr[ni], acc[mi][ni]);
    }
  }

  // epilogue: c in [0,3072): which=c>>10, h=(c>>6)&15, d=c&63
#pragma unroll
  for (int ni = 0; ni < 4; ++ni) {
    const int c = n0 + wn * 64 + ni * 16 + l15;
    const int which = c >> 10;
    const int hd = c & 1023;
    const int h = hd >> 6, d = hd & 63;
#pragma unroll
    for (int mi = 0; mi < 4; ++mi) {
      if (which == 2) {
        // V^T [BH][D=64][N=2048]: r=0..3 -> consecutive nn -> one 8B store
        const int m = m0 + wm * 64 + mi * 16 + kg * 4;
        const int b = m >> 11, nn = m & 2047;
        ushort4 pk;
        pk.x = f2bf(acc[mi][ni][0]);
        pk.y = f2bf(acc[mi][ni][1]);
        pk.z = f2bf(acc[mi][ni][2]);
        pk.w = f2bf(acc[mi][ni][3]);
        *(ushort4*)&vtb[((size_t)(b * 16 + h) * 64 + d) * 2048 + nn] = pk;
      } else {
        unsigned short* dst = (which == 0) ? qb : kb;
        const float sc = (which == 0) ? 0.18033688011112042f : 1.0f;  // 0.125*log2(e) in q
#pragma unroll
        for (int r = 0; r < 4; ++r) {
          const int m = m0 + wm * 64 + mi * 16 + kg * 4 + r;
          const int b = m >> 11, nn = m & 2047;
          dst[(((size_t)(b * 16 + h)) * 2048 + nn) * 64 + d] = f2bf(acc[mi][ni][r] * sc);
        }
      }
    }
  }
}

// ---------------- flash attention (R14-proven): per (bh, qtile of 256 rows), 8 waves ----------------
__global__ __launch_bounds__(512, 4)
void k_attn(const unsigned short* __restrict__ qb,
            const unsigned short* __restrict__ kb,
            const unsigned short* __restrict__ vt,
            unsigned short* __restrict__ ob) {
  __shared__ unsigned short Ks[2][64 * 64];
  __shared__ unsigned short Vs[64 * 64];      // V^T tile: [d][kv], single buffer
  __shared__ unsigned short Ps[8][32][64];    // per-wave P [q][kv], XOR-swizzled
  const int tid = threadIdx.x, lane = tid & 63, w = tid >> 6;   // w = 0..7
  const int l15 = lane & 15, kg = lane >> 4;
  // XCD-aware bijective swizzle: 512 blocks, each XCD owns 8 full bh
  const int flat = blockIdx.x;
  const int sw = (flat & 7) * 64 + (flat >> 3);
  const int qt = sw & 7, bh = sw >> 3;

  const unsigned short* Q = qb + ((size_t)bh * 2048 + qt * 256 + w * 32) * 64;
  vbf8 qf[2][2];
#pragma unroll
  for (int qj = 0; qj < 2; ++qj)
#pragma unroll
    for (int kk = 0; kk < 2; ++kk)
      qf[qj][kk] = *(const vbf8*)(Q + (qj * 16 + l15) * 64 + kk * 32 + kg * 8);

  vbf8 onesv;
#pragma unroll
  for (int i = 0; i < 8; ++i) onesv[i] = (short)0x3F80;  // bf16 1.0

  vf4 oacc[2][4] = {};   // [qj][d-block]: O[q=kg*4+r][d=ni*16+l15]
  vf4 lacc[2] = {};      // row-sum of P per subblock (pure accumulation, m=0)

  const int srow = lane >> 3;
  const int scol = (((lane & 7) ^ srow) * 8);
  const int pswz = (l15 & 7) << 3;
  // each wave stages rows w*8 .. w*8+7 (one gload_lds = 64 lanes x 16B = 8 rows)
  const unsigned short* gKbase = kb + ((size_t)bh * 2048 + w * 8 + srow) * 64 + scol;
  const unsigned short* gVbase = vt + ((size_t)bh * 64 + w * 8 + srow) * 2048 + scol;

#define STAGE_K(t, b) do { \
    GLOAD16(gKbase + (size_t)(t) * 4096, &Ks[b][(w * 8) * 64]); \
  } while (0)
#define STAGE_V(t) do { \
    GLOAD16(gVbase + (size_t)(t) * 64, &Vs[(w * 8) * 64]); \
  } while (0)

  STAGE_K(0, 0);
  asm volatile("s_waitcnt vmcnt(0)" ::: "memory");
  __builtin_amdgcn_s_barrier();
  __builtin_amdgcn_sched_barrier(0);

  for (int kt = 0; kt < 32; ++kt) {
    const int cur = kt & 1;
    STAGE_V(kt);                                   // 1 load (oldest)
    if (kt + 1 < 32) STAGE_K(kt + 1, cur ^ 1);     // 1 load, in flight to iter end

    // hoist K fragments once per tile
    vbf8 kfr[2][4];
#pragma unroll
    for (int kk = 0; kk < 2; ++kk)
#pragma unroll
      for (int ni = 0; ni < 4; ++ni)
        kfr[kk][ni] = *(const vbf8*)&Ks[cur][swz(ni * 16 + l15, kk * 32 + kg * 8)];

    // S^T = K @ Q^T (lane holds S[kv][q=l15]); Q pre-scaled by 0.125*log2e
    vf4 s[2][4] = {};
    __builtin_amdgcn_s_setprio(1);
#pragma unroll
    for (int kk = 0; kk < 2; ++kk)
#pragma unroll
      for (int ni = 0; ni < 4; ++ni) {
        s[0][ni] = mfma16(kfr[kk][ni], qf[0][kk], s[0][ni]);
        s[1][ni] = mfma16(kfr[kk][ni], qf[1][kk], s[1][ni]);
      }
    __builtin_amdgcn_s_setprio(0);

    // P = exp2(S) -> bf16 (m=0: no max, no rescale, exact telescoping)
#pragma unroll
    for (int qj = 0; qj < 2; ++qj)
#pragma unroll
      for (int ni = 0; ni < 4; ++ni) {
        ushort4 pk;
        pk.x = cvt_bf16(__builtin_amdgcn_exp2f(s[qj][ni][0]));
        pk.y = cvt_bf16(__builtin_amdgcn_exp2f(s[qj][ni][1]));
        pk.z = cvt_bf16(__builtin_amdgcn_exp2f(s[qj][ni][2]));
        pk.w = cvt_bf16(__builtin_amdgcn_exp2f(s[qj][ni][3]));
        *(ushort4*)&Ps[w][qj * 16 + l15][(ni * 16 + kg * 4) ^ pswz] = pk;
      }

    // wait: own P-writes (lgkm) + V load (oldest vm); K(t+1) stays in flight
    if (kt + 1 < 32) asm volatile("s_waitcnt vmcnt(1) lgkmcnt(0)" ::: "memory");
    else             asm volatile("s_waitcnt vmcnt(0) lgkmcnt(0)" ::: "memory");
    __builtin_amdgcn_s_barrier();      // all waves' V rows landed
    __builtin_amdgcn_sched_barrier(0); // keep PV ds_reads below the barrier

    // O += P @ V ; l += P @ ones  (V fragments shared across both subblocks)
    __builtin_amdgcn_s_setprio(1);
#pragma unroll
    for (int kk = 0; kk < 2; ++kk) {
      const vbf8 pf0 = *(const vbf8*)&Ps[w][l15][(kk * 32 + kg * 8) ^ pswz];
      const vbf8 pf1 = *(const vbf8*)&Ps[w][16 + l15][(kk * 32 + kg * 8) ^ pswz];
      lacc[0] = mfma16(pf0, onesv, lacc[0]);
      lacc[1] = mfma16(pf1, onesv, lacc[1]);
#pragma unroll
      for (int ni = 0; ni < 4; ++ni) {
        const vbf8 vf = *(const vbf8*)&Vs[swz(ni * 16 + l15, kk * 32 + kg * 8)];
        oacc[0][ni] = mfma16(pf0, vf, oacc[0][ni]);
        oacc[1][ni] = mfma16(pf1, vf, oacc[1][ni]);
      }
    }
    __builtin_amdgcn_s_setprio(0);

    __syncthreads();   // drains K(t+1) (vmcnt 0), frees Vs for next stage
  }
#undef STAGE_K
#undef STAGE_V

  const int b = bh >> 4, h = bh & 15;
#pragma unroll
  for (int qj = 0; qj < 2; ++qj)
#pragma unroll
    for (int r = 0; r < 4; ++r) {
      const float inv = 1.0f / lacc[qj][r];
      const int q = qt * 256 + w * 32 + qj * 16 + kg * 4 + r;
#pragma unroll
      for (int ni = 0; ni < 4; ++ni)
        ob[((size_t)b * 2048 + q) * 1024 + h * 64 + ni * 16 + l15] = cvt_bf16(oacc[qj][ni][r] * inv);
    }
}

// ---------------- GEMM2 (m97 structure): out = attnO @ wout^T + bias (f32 out) ----------------
__global__ __launch_bounds__(256, 2)
void k_gemm_out(const unsigned short* __restrict__ A,
                const unsigned short* __restrict__ B,
                const float* __restrict__ bias,
                float* __restrict__ out) {
  __shared__ unsigned short As[128 * 64];
  __shared__ unsigned short Bs[128 * 64];
  const int tid = threadIdx.x;
  const int lane = tid & 63;
  const int wid = tid >> 6;
  const int wm = wid >> 1, wn = wid & 1;
  // XCD-aware bijective swizzle (nwg = 8*64 = 512, %8==0): 8m x 8n per XCD (4MB, fits L2)
  const int flat = blockIdx.y * 8 + blockIdx.x;
  const int sw = (flat & 7) * 64 + (flat >> 3);
  const int m0 = (sw / 8) * 128;
  const int n0 = (sw % 8) * 128;
  const int l15 = lane & 15, kg = lane >> 4;
  const int srow = wid * 32 + (lane >> 3);
  const int scol = (lane & 7) * 8;

  vf4 acc[4][4] = {};

  for (int kt = 0; kt < 16; ++kt) {
    __syncthreads();
    const unsigned short* gA = A + (size_t)(m0 + srow) * 1024 + kt * 64 + scol;
    const unsigned short* gB = B + (size_t)(n0 + srow) * 1024 + kt * 64 + scol;
    const unsigned ab = (unsigned)(wid * 32 * 64);
#pragma unroll
    for (int i = 0; i < 4; ++i) {
      GLOAD16(gA + (size_t)i * 8 * 1024, &As[ab + i * 8 * 64]);
      GLOAD16(gB + (size_t)i * 8 * 1024, &Bs[ab + i * 8 * 64]);
    }
    __syncthreads();
#pragma unroll
    for (int kk = 0; kk < 2; ++kk) {
      vbf8 af[4], bfr[4];
#pragma unroll
      for (int mi = 0; mi < 4; ++mi)
        af[mi] = *(const vbf8*)&As[(wm * 64 + mi * 16 + l15) * 64 + kk * 32 + kg * 8];
#pragma unroll
      for (int ni = 0; ni < 4; ++ni)
        bfr[ni] = *(const vbf8*)&Bs[(wn * 64 + ni * 16 + l15) * 64 + kk * 32 + kg * 8];
#pragma unroll
      for (int mi = 0; mi < 4; ++mi)
#pragma unroll
        for (int ni = 0; ni < 4; ++ni)
          acc[mi][ni] = mfma16(af[mi], bfr[ni], acc[mi][ni]);
    }
  }

#pragma unroll
  for (int ni = 0; ni < 4; ++ni) {
    const int c = n0 + wn * 64 + ni * 16 + l15;
    const float bv = bias[c];
#pragma unroll
    for (int mi = 0; mi < 4; ++mi) {
#pragma unroll
      for (int r = 0; r < 4; ++r) {
        const int m = m0 + wm * 64 + mi * 16 + kg * 4 + r;
        out[(size_t)m * 1024 + c] = acc[mi][ni][r] + bv;
      }
    }
  }
}

extern "C" void kernel_launch(void* const* d_in, const int* in_sizes, int n_in,
                              void* d_out, int out_size, void* d_ws, size_t ws_size,
                              hipStream_t stream) {
  const float* x     = (const float*)d_in[0];
  const float* w_qkv = (const float*)d_in[1];
  const float* w_out = (const float*)d_in[2];
  const float* b_out = (const float*)d_in[3];
  float* out = (float*)d_out;

  char* ws = (char*)d_ws;
  unsigned short* xbf   = (unsigned short*)(ws);                       // 16 MB (aliased as attnO later)
  unsigned short* wqkvb = (unsigned short*)(ws + 16777216);            // 6 MB
  unsigned short* woutb = (unsigned short*)(ws + 23068672);            // 2 MB
  unsigned short* qbuf  = (unsigned short*)(ws + 25165824);            // 16 MB
  unsigned short* kbuf  = (unsigned short*)(ws + 41943040);            // 16 MB
  unsigned short* vtbuf = (unsigned short*)(ws + 75497472);            // 16 MB (V^T, written by gemm_qkv)
  unsigned short* aob   = xbf;  // attn output aliases xbf (xbf dead after GEMM1)

  k_cvt_all<<<2048, 256, 0, stream>>>(x, xbf, w_qkv, wqkvb, w_out, woutb);

  k_gemm_qkv<<<dim3(24, 64), 256, 0, stream>>>(xbf, wqkvb, qbuf, kbuf, vtbuf);
  k_attn<<<dim3(512), 512, 0, stream>>>(qbuf, kbuf, vtbuf, aob);
  k_gemm_out<<<dim3(8, 64), 256, 0, stream>>>(aob, woutb, b_out, out);
}